// Round 3
// baseline (1343.963 us; speedup 1.0000x reference)
//
#include <hip/hip_runtime.h>

typedef unsigned short ushort_t;
typedef unsigned int uint32;
typedef __attribute__((ext_vector_type(8))) short short8;
typedef __attribute__((ext_vector_type(4))) float f32x4;

#define HID 256
#define MI 128
// p1 is pre-scaled by ALPHA = 2/ln2, so sim MFMA output = cos*2/ln2 and
// exp(cos/T) = exp2(acc) directly. Edge ln-logit: s = 2*cos = d * ln2.
#define ALPHA 2.8853900817779268f
#define LN2F 0.69314718055994531f

#define AS1 __attribute__((address_space(1)))
#define AS3 __attribute__((address_space(3)))

__device__ __forceinline__ float bflo(uint32 u) { return __uint_as_float(u << 16); }
__device__ __forceinline__ float bfhi(uint32 u) { return __uint_as_float(u & 0xffff0000u); }
__device__ __forceinline__ ushort_t f2bf(float f) {
  uint32 u = __float_as_uint(f);
  u += 0x7fffu + ((u >> 16) & 1u);   // RNE
  return (ushort_t)(u >> 16);
}

// ---------------------------------------------------------------------------
// Kernel 1: p = l2norm(relu(h @ W + b)) -> bf16 (p1 additionally * ALPHA).
// ---------------------------------------------------------------------------
__global__ __launch_bounds__(256) void proj_norm_kernel(
    const float* __restrict__ h1, const float* __restrict__ h2,
    const float* __restrict__ W, const float* __restrict__ b,
    ushort_t* __restrict__ p1b, ushort_t* __restrict__ p2b, int n)
{
  __shared__ float sh[64 * HID];   // 64 KB
  int t = threadIdx.x;
  long R0 = (long)blockIdx.x * 64;
  const float* src = (R0 < n) ? (h1 + R0 * HID) : (h2 + (R0 - n) * HID);
  ushort_t* dst = (R0 < n) ? (p1b + R0 * MI) : (p2b + (R0 - n) * MI);
  float scale = (R0 < n) ? ALPHA : 1.0f;

  const float4* g4 = (const float4*)src;
  float4* s4 = (float4*)sh;
  #pragma unroll
  for (int it = 0; it < 16; ++it) s4[it * 256 + t] = g4[it * 256 + t];
  __syncthreads();

  int tc = t & 31, tr = t >> 5;
  float acc[8][4];
  float4 bb = ((const float4*)b)[tc];
  #pragma unroll
  for (int rr = 0; rr < 8; ++rr) {
    acc[rr][0] = bb.x; acc[rr][1] = bb.y; acc[rr][2] = bb.z; acc[rr][3] = bb.w;
  }
  const float4* W4 = (const float4*)W;
  const float* shr = sh + tr * 8 * HID;
  #pragma unroll 8
  for (int k = 0; k < HID; ++k) {
    float4 w = W4[k * 32 + tc];
    #pragma unroll
    for (int rr = 0; rr < 8; ++rr) {
      float hv = shr[rr * HID + k];
      acc[rr][0] += hv * w.x;
      acc[rr][1] += hv * w.y;
      acc[rr][2] += hv * w.z;
      acc[rr][3] += hv * w.w;
    }
  }
  #pragma unroll
  for (int rr = 0; rr < 8; ++rr) {
    float v0 = fmaxf(acc[rr][0], 0.f), v1 = fmaxf(acc[rr][1], 0.f);
    float v2 = fmaxf(acc[rr][2], 0.f), v3 = fmaxf(acc[rr][3], 0.f);
    float ss = v0 * v0 + v1 * v1 + v2 * v2 + v3 * v3;
    #pragma unroll
    for (int m = 1; m <= 16; m <<= 1) ss += __shfl_xor(ss, m, 64);
    float rn = rsqrtf(ss) * scale;
    ushort4 o;
    o.x = f2bf(v0 * rn); o.y = f2bf(v1 * rn); o.z = f2bf(v2 * rn); o.w = f2bf(v3 * rn);
    *(ushort4*)(dst + (tr * 8 + rr) * MI + tc * 4) = o;
  }
}

// ---------------------------------------------------------------------------
// Kernel 2: barrier-free sim sweep.
// Block = (i-strip of 2048 rows) x (j-chunk of 128 cols). B tile staged to
// LDS ONCE (32 KB, XOR-swizzled); then each wave independently processes 8
// units of 64 rows: A frags global->VGPR, 128 MFMA, exp epilogue. No
// __syncthreads / no vmcnt(0) drain / no LDS atomics in the main loop.
// Col partials live in registers across the whole sweep.
// grid(8,128): linear id % 8 == blockIdx.x == i-strip -> one strip per XCD.
// ---------------------------------------------------------------------------
__global__ __launch_bounds__(256, 4) void sim_kernel(
    const ushort_t* __restrict__ p1b, const ushort_t* __restrict__ p2b,
    float* __restrict__ rowsum, float* __restrict__ colsum)
{
  __shared__ __align__(16) unsigned char ldsB[32768];
  __shared__ float colred[512];
  int t = threadIdx.x;
  int lane = t & 63, w = t >> 6;
  int lr = lane & 15, lg = lane >> 4;
  int i_base = blockIdx.x * 2048;
  int j0 = blockIdx.y * 128;

  // Stage B tile once: 2048 granules of 16B, global side XOR-permuted so
  // LDS slot (row, g) holds global granule g^(row&15).
  #pragma unroll
  for (int s = 0; s < 8; ++s) {
    int L = s * 256 + t;
    int row = L >> 4, gs = L & 15;
    const ushort_t* gp = p2b + (size_t)(j0 + row) * MI + ((gs ^ (row & 15)) << 3);
    unsigned char* lp = ldsB + s * 4096 + w * 1024;   // wave-uniform base
    __builtin_amdgcn_global_load_lds((const AS1 void*)gp, (AS3 void*)lp, 16, 0, 0);
  }
  __syncthreads();

  float cp[8];
  #pragma unroll
  for (int c = 0; c < 8; ++c) cp[c] = 0.f;

  for (int u = 0; u < 8; ++u) {
    int rowbase = i_base + u * 256 + w * 64;
    short8 afr[4][4];
    #pragma unroll
    for (int rt = 0; rt < 4; ++rt)
      #pragma unroll
      for (int kt = 0; kt < 4; ++kt)
        afr[rt][kt] = *(const short8*)(p1b + (size_t)(rowbase + rt * 16 + lr) * MI + kt * 32 + lg * 8);

    float rs[4][4];
    #pragma unroll
    for (int rt = 0; rt < 4; ++rt)
      #pragma unroll
      for (int r = 0; r < 4; ++r) rs[rt][r] = 0.f;

    #pragma unroll
    for (int ch = 0; ch < 8; ++ch) {
      f32x4 acc[4];
      #pragma unroll
      for (int rt = 0; rt < 4; ++rt) acc[rt] = (f32x4){0.f, 0.f, 0.f, 0.f};
      #pragma unroll
      for (int kt = 0; kt < 4; ++kt) {
        int ncol = ch * 16 + lr;
        int g = kt * 4 + lg;
        short8 bf = *(const short8*)(ldsB + ncol * 256 + ((g ^ (ncol & 15)) << 4));
        #pragma unroll
        for (int rt = 0; rt < 4; ++rt)
          acc[rt] = __builtin_amdgcn_mfma_f32_16x16x32_bf16(afr[rt][kt], bf, acc[rt], 0, 0, 0);
      }
      // D layout: col = ch*16 + lr, row = rt*16 + lg*4 + r.
      #pragma unroll
      for (int rt = 0; rt < 4; ++rt)
        #pragma unroll
        for (int r = 0; r < 4; ++r) {
          float e = __builtin_amdgcn_exp2f(acc[rt][r]);
          rs[rt][r] += e;
          cp[ch] += e;
        }
    }
    // Row flush: reduce over the 16 lr-lanes, 4-lane-wide global atomic.
    #pragma unroll
    for (int rt = 0; rt < 4; ++rt)
      #pragma unroll
      for (int r = 0; r < 4; ++r) {
        float v = rs[rt][r];
        v += __shfl_xor(v, 1, 64);
        v += __shfl_xor(v, 2, 64);
        v += __shfl_xor(v, 4, 64);
        v += __shfl_xor(v, 8, 64);
        if (lr == 0) atomicAdd(&rowsum[rowbase + rt * 16 + lg * 4 + r], v);
      }
  }

  // Col flush: reduce over lg groups in-register, then one LDS pass.
  #pragma unroll
  for (int c = 0; c < 8; ++c) {
    float v = cp[c];
    v += __shfl_xor(v, 16, 64);
    v += __shfl_xor(v, 32, 64);
    if (lg == 0) colred[w * 128 + c * 16 + lr] = v;
  }
  __syncthreads();
  if (t < 128) {
    float v = colred[t] + colred[128 + t] + colred[256 + t] + colred[384 + t];
    atomicAdd(&colsum[j0 + t], v);
  }
}

// ---------------------------------------------------------------------------
// Kernel 3: per-edge positive logits, both directions.
// d = ALPHA*cos (ALPHA folded into p1b). exp term = exp2(d); ln-logit = d*ln2.
// ---------------------------------------------------------------------------
__global__ __launch_bounds__(256) void edge_kernel(
    const int* __restrict__ pos_row, const int* __restrict__ pos_col,
    const ushort_t* __restrict__ p1b, const ushort_t* __restrict__ p2b,
    float* __restrict__ psum1, float* __restrict__ psum2,
    float* __restrict__ srow1, float* __restrict__ srow2,
    float* __restrict__ cntb, int E)
{
  int e = blockIdx.x * 256 + threadIdx.x;
  if (e >= E) return;
  int r = pos_row[e], c = pos_col[e];
  const uint4* a1 = (const uint4*)(p1b + (size_t)r * MI);
  const uint4* b1 = (const uint4*)(p2b + (size_t)c * MI);
  const uint4* a2 = (const uint4*)(p1b + (size_t)c * MI);
  const uint4* b2 = (const uint4*)(p2b + (size_t)r * MI);
  float d1 = 0.f, d2 = 0.f;
  #pragma unroll
  for (int it = 0; it < 16; ++it) {
    uint4 x = a1[it], y = b1[it];
    d1 += bflo(x.x) * bflo(y.x) + bfhi(x.x) * bfhi(y.x);
    d1 += bflo(x.y) * bflo(y.y) + bfhi(x.y) * bfhi(y.y);
    d1 += bflo(x.z) * bflo(y.z) + bfhi(x.z) * bfhi(y.z);
    d1 += bflo(x.w) * bflo(y.w) + bfhi(x.w) * bfhi(y.w);
    uint4 u = a2[it], v = b2[it];
    d2 += bflo(u.x) * bflo(v.x) + bfhi(u.x) * bfhi(v.x);
    d2 += bflo(u.y) * bflo(v.y) + bfhi(u.y) * bfhi(v.y);
    d2 += bflo(u.z) * bflo(v.z) + bfhi(u.z) * bfhi(v.z);
    d2 += bflo(u.w) * bflo(v.w) + bfhi(u.w) * bfhi(v.w);
  }
  float e1 = __builtin_amdgcn_exp2f(d1);
  float e2 = __builtin_amdgcn_exp2f(d2);
  atomicAdd(&psum1[r], e1);
  atomicAdd(&srow1[r], d1 * LN2F);
  atomicAdd(&psum2[r], e2);
  atomicAdd(&srow2[r], d2 * LN2F);
  atomicAdd(&cntb[r], 1.0f);
}

// ---------------------------------------------------------------------------
// Kernel 4: loss contribution per row, 64 blocks, atomicAdd into out[0].
// out must be zeroed before launch (hipMemsetAsync in kernel_launch).
// ---------------------------------------------------------------------------
__global__ __launch_bounds__(256) void finalize_kernel(
    const float* __restrict__ rowsum, const float* __restrict__ colsum,
    const float* __restrict__ psum1, const float* __restrict__ psum2,
    const float* __restrict__ srow1, const float* __restrict__ srow2,
    const float* __restrict__ cntb, float* __restrict__ out, int n)
{
  __shared__ float sred[4];
  int r = blockIdx.x * 256 + threadIdx.x;
  float local = 0.f;
  if (r < n) {
    float inv = 1.0f / cntb[r];
    float d1 = rowsum[r] - psum1[r];
    float d2 = colsum[r] - psum2[r];
    local = srow1[r] * inv - __builtin_amdgcn_logf(d1) * LN2F
          + srow2[r] * inv - __builtin_amdgcn_logf(d2) * LN2F;
  }
  #pragma unroll
  for (int m = 1; m <= 32; m <<= 1) local += __shfl_xor(local, m, 64);
  int lane = threadIdx.x & 63, wv = threadIdx.x >> 6;
  if (lane == 0) sred[wv] = local;
  __syncthreads();
  if (threadIdx.x == 0) {
    float tot = sred[0] + sred[1] + sred[2] + sred[3];
    atomicAdd(out, -tot / (2.0f * n));
  }
}

extern "C" void kernel_launch(void* const* d_in, const int* in_sizes, int n_in,
                              void* d_out, int out_size, void* d_ws, size_t ws_size,
                              hipStream_t stream)
{
  const float* h1 = (const float*)d_in[0];
  const float* h2 = (const float*)d_in[1];
  const float* W  = (const float*)d_in[2];
  const float* b  = (const float*)d_in[3];
  const int* pos_row = (const int*)d_in[4];
  const int* pos_col = (const int*)d_in[5];
  int n = in_sizes[0] / HID;      // 16384
  int E = in_sizes[4];            // 65536
  float* out = (float*)d_out;

  char* ws = (char*)d_ws;
  ushort_t* p1b = (ushort_t*)ws;                       // n*128 bf16 = 4 MB
  ushort_t* p2b = p1b + (size_t)n * MI;                // 4 MB
  float* fbase  = (float*)(ws + (size_t)2 * n * MI * sizeof(ushort_t));
  float* rowsum = fbase;
  float* colsum = rowsum + n;
  float* psum1  = colsum + n;
  float* psum2  = psum1 + n;
  float* srow1  = psum2 + n;
  float* srow2  = srow1 + n;
  float* cntb   = srow2 + n;

  hipMemsetAsync(fbase, 0, (size_t)7 * n * sizeof(float), stream);
  hipMemsetAsync(out, 0, sizeof(float), stream);
  proj_norm_kernel<<<2 * n / 64, 256, 0, stream>>>(h1, h2, W, b, p1b, p2b, n);
  dim3 g2(8, 128);                // (i-strips, j-chunks): id%8 = i-strip = XCD
  sim_kernel<<<g2, 256, 0, stream>>>(p1b, p2b, rowsum, colsum);
  edge_kernel<<<(E + 255) / 256, 256, 0, stream>>>(pos_row, pos_col, p1b, p2b,
                                                   psum1, psum2, srow1, srow2, cntb, E);
  finalize_kernel<<<(n + 255) / 256, 256, 0, stream>>>(rowsum, colsum, psum1, psum2,
                                                       srow1, srow2, cntb, out, n);
}

// Round 4
// 551.624 us; speedup vs baseline: 2.4364x; 2.4364x over previous
//
#include <hip/hip_runtime.h>

typedef unsigned short ushort_t;
typedef unsigned int uint32;
typedef __attribute__((ext_vector_type(8))) short short8;
typedef __attribute__((ext_vector_type(4))) float f32x4;
typedef __attribute__((ext_vector_type(2))) float f32x2;

#define HID 256
#define MI 128
// p1 is pre-scaled by ALPHA = 2/ln2, so sim MFMA output = cos*2/ln2 and
// exp(cos/T) = exp2(acc) directly. Edge ln-logit: s = 2*cos = d * ln2.
#define ALPHA 2.8853900817779268f
#define LN2F 0.69314718055994531f

#define AS1 __attribute__((address_space(1)))
#define AS3 __attribute__((address_space(3)))

__device__ __forceinline__ float bflo(uint32 u) { return __uint_as_float(u << 16); }
__device__ __forceinline__ float bfhi(uint32 u) { return __uint_as_float(u & 0xffff0000u); }
__device__ __forceinline__ ushort_t f2bf(float f) {
  uint32 u = __float_as_uint(f);
  u += 0x7fffu + ((u >> 16) & 1u);   // RNE
  return (ushort_t)(u >> 16);
}

// ---------------------------------------------------------------------------
// Kernel 0: Wt[n][k] (bf16) <- W[k][n] (f32). B-fragment-friendly layout.
// ---------------------------------------------------------------------------
__global__ __launch_bounds__(256) void wprep_kernel(
    const float* __restrict__ W, ushort_t* __restrict__ Wtb)
{
  int idx = blockIdx.x * 256 + threadIdx.x;   // 32768 elems
  int k = idx >> 7, nn = idx & 127;
  Wtb[nn * HID + k] = f2bf(W[k * MI + nn]);   // read coalesced over nn
}

// ---------------------------------------------------------------------------
// Kernel 1: p = l2norm(relu(h @ W + b)) -> bf16 (p1 additionally * ALPHA).
// MFMA version: h cast to bf16 during LDS staging (XOR-swizzled), W-frags
// read from pre-transposed Wtb (64 KB, L2-hot). 64 rows/block, wave=16 rows.
// ---------------------------------------------------------------------------
__global__ __launch_bounds__(256) void proj_kernel(
    const float* __restrict__ h1, const float* __restrict__ h2,
    const ushort_t* __restrict__ Wtb, const float* __restrict__ b,
    ushort_t* __restrict__ p1b, ushort_t* __restrict__ p2b, int n)
{
  __shared__ __align__(16) unsigned char hb[64 * 512];   // 64 rows x 256 bf16
  int t = threadIdx.x;
  int lane = t & 63, w = t >> 6;
  int lr = lane & 15, lg = lane >> 4;
  long R0 = (long)blockIdx.x * 64;
  const float* src = (R0 < n) ? (h1 + R0 * HID) : (h2 + (R0 - n) * HID);
  ushort_t* dst = (R0 < n) ? (p1b + R0 * MI) : (p2b + (R0 - n) * MI);
  float scale = (R0 < n) ? ALPHA : 1.0f;

  // Bias values for this lane's cols (b is tiny, L2-hot).
  float bb[8];
  #pragma unroll
  for (int ch = 0; ch < 8; ++ch) bb[ch] = b[ch * 16 + lr];

  // Stage + convert: 4096 float4 reads, swizzled bf16 writes.
  const float4* g4 = (const float4*)src;
  #pragma unroll
  for (int i = 0; i < 16; ++i) {
    int idx4 = i * 256 + t;
    float4 v = g4[idx4];
    int row = idx4 >> 6;             // 64 float4 per 256-elem row
    int k0 = (idx4 & 63) * 4;
    int gr = k0 >> 3;                // 16B granule index (8 bf16)
    int off = row * 512 + ((gr ^ (row & 15)) << 4) + (k0 & 7) * 2;
    uint32 lo = (uint32)f2bf(v.x) | ((uint32)f2bf(v.y) << 16);
    uint32 hi = (uint32)f2bf(v.z) | ((uint32)f2bf(v.w) << 16);
    uint2 pk; pk.x = lo; pk.y = hi;
    *(uint2*)(hb + off) = pk;
  }
  __syncthreads();

  // A frags: this wave's 16 rows x K=256 (8 kt) from LDS.
  short8 afr[8];
  #pragma unroll
  for (int kt = 0; kt < 8; ++kt) {
    int row = w * 16 + lr;
    int g = kt * 4 + lg;
    afr[kt] = *(const short8*)(hb + row * 512 + ((g ^ (row & 15)) << 4));
  }

  f32x4 acc[8];
  #pragma unroll
  for (int ch = 0; ch < 8; ++ch) acc[ch] = (f32x4){0.f, 0.f, 0.f, 0.f};
  #pragma unroll
  for (int ch = 0; ch < 8; ++ch) {
    #pragma unroll
    for (int kt = 0; kt < 8; ++kt) {
      short8 bf = *(const short8*)(Wtb + (size_t)(ch * 16 + lr) * HID + kt * 32 + lg * 8);
      acc[ch] = __builtin_amdgcn_mfma_f32_16x16x32_bf16(afr[kt], bf, acc[ch], 0, 0, 0);
    }
  }

  // Epilogue: rows w*16 + lg*4 + r, cols ch*16 + lr.
  #pragma unroll
  for (int r = 0; r < 4; ++r) {
    float v[8];
    float ss = 0.f;
    #pragma unroll
    for (int ch = 0; ch < 8; ++ch) {
      v[ch] = fmaxf(acc[ch][r] + bb[ch], 0.f);
      ss += v[ch] * v[ch];
    }
    ss += __shfl_xor(ss, 1, 64);
    ss += __shfl_xor(ss, 2, 64);
    ss += __shfl_xor(ss, 4, 64);
    ss += __shfl_xor(ss, 8, 64);
    float rn = rsqrtf(ss) * scale;
    int row = w * 16 + lg * 4 + r;
    #pragma unroll
    for (int ch = 0; ch < 8; ++ch)
      dst[(size_t)row * MI + ch * 16 + lr] = f2bf(v[ch] * rn);
  }
}

// ---------------------------------------------------------------------------
// Kernel 2: barrier-free sim sweep (rt=2 — no-spill register footprint).
// Block = (i-strip of 2048 rows) x (j-chunk of 128 cols). B tile staged to
// LDS ONCE (32 KB, XOR-swizzled); each wave independently processes 16
// units of 32 rows: A frags global->VGPR, 64 MFMA, exp epilogue. No
// __syncthreads / no vmcnt(0) drains / no LDS atomics in the main loop.
// Col partials in registers (float2 -> v_pk_add_f32) across the whole sweep.
// grid(8,128): linear id % 8 == blockIdx.x == i-strip -> one strip per XCD.
// ---------------------------------------------------------------------------
__global__ __launch_bounds__(256, 4) void sim_kernel(
    const ushort_t* __restrict__ p1b, const ushort_t* __restrict__ p2b,
    float* __restrict__ rowsum, float* __restrict__ colsum)
{
  __shared__ __align__(16) unsigned char ldsB[32768];
  __shared__ float colred[512];
  int t = threadIdx.x;
  int lane = t & 63, w = t >> 6;
  int lr = lane & 15, lg = lane >> 4;
  int i_base = blockIdx.x * 2048;
  int j0 = blockIdx.y * 128;

  // Stage B tile once: 2048 granules of 16B, global side XOR-permuted so
  // LDS slot (row, g) holds global granule g^(row&15).
  #pragma unroll
  for (int s = 0; s < 8; ++s) {
    int L = s * 256 + t;
    int row = L >> 4, gs = L & 15;
    const ushort_t* gp = p2b + (size_t)(j0 + row) * MI + ((gs ^ (row & 15)) << 3);
    unsigned char* lp = ldsB + s * 4096 + w * 1024;   // wave-uniform base
    __builtin_amdgcn_global_load_lds((const AS1 void*)gp, (AS3 void*)lp, 16, 0, 0);
  }
  __syncthreads();

  f32x2 cp2[8];
  #pragma unroll
  for (int c = 0; c < 8; ++c) cp2[c] = (f32x2){0.f, 0.f};

  for (int u = 0; u < 16; ++u) {
    int rowbase = i_base + u * 128 + w * 32;
    short8 afr[2][4];
    #pragma unroll
    for (int rt = 0; rt < 2; ++rt)
      #pragma unroll
      for (int kt = 0; kt < 4; ++kt)
        afr[rt][kt] = *(const short8*)(p1b + (size_t)(rowbase + rt * 16 + lr) * MI + kt * 32 + lg * 8);

    f32x2 rs2[2][2];
    #pragma unroll
    for (int rt = 0; rt < 2; ++rt) {
      rs2[rt][0] = (f32x2){0.f, 0.f};
      rs2[rt][1] = (f32x2){0.f, 0.f};
    }

    #pragma unroll
    for (int ch = 0; ch < 8; ++ch) {
      f32x4 acc[2];
      acc[0] = (f32x4){0.f, 0.f, 0.f, 0.f};
      acc[1] = (f32x4){0.f, 0.f, 0.f, 0.f};
      #pragma unroll
      for (int kt = 0; kt < 4; ++kt) {
        int ncol = ch * 16 + lr;
        int g = kt * 4 + lg;
        short8 bf = *(const short8*)(ldsB + ncol * 256 + ((g ^ (ncol & 15)) << 4));
        acc[0] = __builtin_amdgcn_mfma_f32_16x16x32_bf16(afr[0][kt], bf, acc[0], 0, 0, 0);
        acc[1] = __builtin_amdgcn_mfma_f32_16x16x32_bf16(afr[1][kt], bf, acc[1], 0, 0, 0);
      }
      // D layout: col = ch*16 + lr, row = rt*16 + lg*4 + r.
      #pragma unroll
      for (int rt = 0; rt < 2; ++rt) {
        f32x2 e01, e23;
        e01[0] = __builtin_amdgcn_exp2f(acc[rt][0]);
        e01[1] = __builtin_amdgcn_exp2f(acc[rt][1]);
        e23[0] = __builtin_amdgcn_exp2f(acc[rt][2]);
        e23[1] = __builtin_amdgcn_exp2f(acc[rt][3]);
        rs2[rt][0] += e01;
        rs2[rt][1] += e23;
        cp2[ch] += e01;
        cp2[ch] += e23;
      }
    }
    // Row flush: butterfly over the 16 lr-lanes, 4-lane-wide global atomic.
    #pragma unroll
    for (int rt = 0; rt < 2; ++rt)
      #pragma unroll
      for (int j = 0; j < 2; ++j)
        #pragma unroll
        for (int s = 0; s < 2; ++s) {
          float v = rs2[rt][j][s];
          v += __shfl_xor(v, 1, 64);
          v += __shfl_xor(v, 2, 64);
          v += __shfl_xor(v, 4, 64);
          v += __shfl_xor(v, 8, 64);
          if (lr == 0) atomicAdd(&rowsum[rowbase + rt * 16 + lg * 4 + j * 2 + s], v);
        }
  }

  // Col flush: reduce over lg groups in-register, then one LDS pass.
  #pragma unroll
  for (int c = 0; c < 8; ++c) {
    float v = cp2[c][0] + cp2[c][1];
    v += __shfl_xor(v, 16, 64);
    v += __shfl_xor(v, 32, 64);
    if (lg == 0) colred[w * 128 + c * 16 + lr] = v;
  }
  __syncthreads();
  if (t < 128) {
    float v = colred[t] + colred[128 + t] + colred[256 + t] + colred[384 + t];
    atomicAdd(&colsum[j0 + t], v);
  }
}

// ---------------------------------------------------------------------------
// Kernel 3: per-edge positive logits, both directions.
// d = ALPHA*cos (ALPHA folded into p1b). exp term = exp2(d); ln-logit = d*ln2.
// ---------------------------------------------------------------------------
__global__ __launch_bounds__(256) void edge_kernel(
    const int* __restrict__ pos_row, const int* __restrict__ pos_col,
    const ushort_t* __restrict__ p1b, const ushort_t* __restrict__ p2b,
    float* __restrict__ psum1, float* __restrict__ psum2,
    float* __restrict__ srow1, float* __restrict__ srow2,
    float* __restrict__ cntb, int E)
{
  int e = blockIdx.x * 256 + threadIdx.x;
  if (e >= E) return;
  int r = pos_row[e], c = pos_col[e];
  const uint4* a1 = (const uint4*)(p1b + (size_t)r * MI);
  const uint4* b1 = (const uint4*)(p2b + (size_t)c * MI);
  const uint4* a2 = (const uint4*)(p1b + (size_t)c * MI);
  const uint4* b2 = (const uint4*)(p2b + (size_t)r * MI);
  float d1 = 0.f, d2 = 0.f;
  #pragma unroll
  for (int it = 0; it < 16; ++it) {
    uint4 x = a1[it], y = b1[it];
    d1 += bflo(x.x) * bflo(y.x) + bfhi(x.x) * bfhi(y.x);
    d1 += bflo(x.y) * bflo(y.y) + bfhi(x.y) * bfhi(y.y);
    d1 += bflo(x.z) * bflo(y.z) + bfhi(x.z) * bfhi(y.z);
    d1 += bflo(x.w) * bflo(y.w) + bfhi(x.w) * bfhi(y.w);
    uint4 u = a2[it], v = b2[it];
    d2 += bflo(u.x) * bflo(v.x) + bfhi(u.x) * bfhi(v.x);
    d2 += bflo(u.y) * bflo(v.y) + bfhi(u.y) * bfhi(v.y);
    d2 += bflo(u.z) * bflo(v.z) + bfhi(u.z) * bfhi(v.z);
    d2 += bflo(u.w) * bflo(v.w) + bfhi(u.w) * bfhi(v.w);
  }
  float e1 = __builtin_amdgcn_exp2f(d1);
  float e2 = __builtin_amdgcn_exp2f(d2);
  atomicAdd(&psum1[r], e1);
  atomicAdd(&srow1[r], d1 * LN2F);
  atomicAdd(&psum2[r], e2);
  atomicAdd(&srow2[r], d2 * LN2F);
  atomicAdd(&cntb[r], 1.0f);
}

// ---------------------------------------------------------------------------
// Kernel 4: loss contribution per row, atomicAdd into out[0] (pre-zeroed).
// ---------------------------------------------------------------------------
__global__ __launch_bounds__(256) void finalize_kernel(
    const float* __restrict__ rowsum, const float* __restrict__ colsum,
    const float* __restrict__ psum1, const float* __restrict__ psum2,
    const float* __restrict__ srow1, const float* __restrict__ srow2,
    const float* __restrict__ cntb, float* __restrict__ out, int n)
{
  __shared__ float sred[4];
  int r = blockIdx.x * 256 + threadIdx.x;
  float local = 0.f;
  if (r < n) {
    float inv = 1.0f / cntb[r];
    float d1 = rowsum[r] - psum1[r];
    float d2 = colsum[r] - psum2[r];
    local = srow1[r] * inv - __builtin_amdgcn_logf(d1) * LN2F
          + srow2[r] * inv - __builtin_amdgcn_logf(d2) * LN2F;
  }
  #pragma unroll
  for (int m = 1; m <= 32; m <<= 1) local += __shfl_xor(local, m, 64);
  int lane = threadIdx.x & 63, wv = threadIdx.x >> 6;
  if (lane == 0) sred[wv] = local;
  __syncthreads();
  if (threadIdx.x == 0) {
    float tot = sred[0] + sred[1] + sred[2] + sred[3];
    atomicAdd(out, -tot / (2.0f * n));
  }
}

extern "C" void kernel_launch(void* const* d_in, const int* in_sizes, int n_in,
                              void* d_out, int out_size, void* d_ws, size_t ws_size,
                              hipStream_t stream)
{
  const float* h1 = (const float*)d_in[0];
  const float* h2 = (const float*)d_in[1];
  const float* W  = (const float*)d_in[2];
  const float* b  = (const float*)d_in[3];
  const int* pos_row = (const int*)d_in[4];
  const int* pos_col = (const int*)d_in[5];
  int n = in_sizes[0] / HID;      // 16384
  int E = in_sizes[4];            // 65536
  float* out = (float*)d_out;

  char* ws = (char*)d_ws;
  ushort_t* p1b = (ushort_t*)ws;                       // n*128 bf16 = 4 MB
  ushort_t* p2b = p1b + (size_t)n * MI;                // 4 MB
  float* fbase  = (float*)(ws + (size_t)2 * n * MI * sizeof(ushort_t));
  float* rowsum = fbase;
  float* colsum = rowsum + n;
  float* psum1  = colsum + n;
  float* psum2  = psum1 + n;
  float* srow1  = psum2 + n;
  float* srow2  = srow1 + n;
  float* cntb   = srow2 + n;
  ushort_t* Wtb = (ushort_t*)(cntb + n);               // 128x256 bf16 = 64 KB

  hipMemsetAsync(fbase, 0, (size_t)7 * n * sizeof(float), stream);
  hipMemsetAsync(out, 0, sizeof(float), stream);
  wprep_kernel<<<HID * MI / 256, 256, 0, stream>>>(W, Wtb);
  proj_kernel<<<2 * n / 64, 256, 0, stream>>>(h1, h2, Wtb, b, p1b, p2b, n);
  dim3 g2(8, 128);                // (i-strips, j-chunks): id%8 = i-strip = XCD
  sim_kernel<<<g2, 256, 0, stream>>>(p1b, p2b, rowsum, colsum);
  edge_kernel<<<(E + 255) / 256, 256, 0, stream>>>(pos_row, pos_col, p1b, p2b,
                                                   psum1, psum2, srow1, srow2, cntb, E);
  finalize_kernel<<<(n + 255) / 256, 256, 0, stream>>>(rowsum, colsum, psum1, psum2,
                                                       srow1, srow2, cntb, out, n);
}

// Round 5
// 226.510 us; speedup vs baseline: 5.9333x; 2.4353x over previous
//
#include <hip/hip_runtime.h>

typedef unsigned short ushort_t;
typedef unsigned int uint32;
typedef __attribute__((ext_vector_type(8))) short short8;
typedef __attribute__((ext_vector_type(4))) float f32x4;
typedef __attribute__((ext_vector_type(2))) float f32x2;

#define HID 256
#define MI 128
// p1 is pre-scaled by ALPHA = 2/ln2, so sim MFMA output = cos*2/ln2 and
// exp(cos/T) = exp2(acc) directly. Edge ln-logit: s = 2*cos = d * ln2.
#define ALPHA 2.8853900817779268f
#define LN2F 0.69314718055994531f

#define AS1 __attribute__((address_space(1)))
#define AS3 __attribute__((address_space(3)))

__device__ __forceinline__ float bflo(uint32 u) { return __uint_as_float(u << 16); }
__device__ __forceinline__ float bfhi(uint32 u) { return __uint_as_float(u & 0xffff0000u); }
__device__ __forceinline__ ushort_t f2bf(float f) {
  uint32 u = __float_as_uint(f);
  u += 0x7fffu + ((u >> 16) & 1u);   // RNE
  return (ushort_t)(u >> 16);
}

// ---------------------------------------------------------------------------
// Kernel 0 (prep): Wt[n][k] (bf16) <- W[k][n] (f32)  AND  zero fbase[7n].
// ---------------------------------------------------------------------------
__global__ __launch_bounds__(256) void prep_kernel(
    const float* __restrict__ W, ushort_t* __restrict__ Wtb,
    float* __restrict__ fbase, int nz)
{
  int idx = blockIdx.x * 256 + threadIdx.x;
  if (idx < HID * MI) {
    int k = idx >> 7, nn = idx & 127;
    Wtb[nn * HID + k] = f2bf(W[k * MI + nn]);   // read coalesced over nn
  }
  if (idx < nz) fbase[idx] = 0.f;
}

// ---------------------------------------------------------------------------
// Kernel 1: p = l2norm(relu(h @ W + b)) -> bf16 (p1 additionally * ALPHA).
// MFMA version: h cast to bf16 during LDS staging (XOR-swizzled), W-frags
// read from pre-transposed Wtb (64 KB, L2-hot). 64 rows/block, wave=16 rows.
// ---------------------------------------------------------------------------
__global__ __launch_bounds__(256) void proj_kernel(
    const float* __restrict__ h1, const float* __restrict__ h2,
    const ushort_t* __restrict__ Wtb, const float* __restrict__ b,
    ushort_t* __restrict__ p1b, ushort_t* __restrict__ p2b, int n)
{
  __shared__ __align__(16) unsigned char hb[64 * 512];   // 64 rows x 256 bf16
  int t = threadIdx.x;
  int lane = t & 63, w = t >> 6;
  int lr = lane & 15, lg = lane >> 4;
  long R0 = (long)blockIdx.x * 64;
  const float* src = (R0 < n) ? (h1 + R0 * HID) : (h2 + (R0 - n) * HID);
  ushort_t* dst = (R0 < n) ? (p1b + R0 * MI) : (p2b + (R0 - n) * MI);
  float scale = (R0 < n) ? ALPHA : 1.0f;

  float bb[8];
  #pragma unroll
  for (int ch = 0; ch < 8; ++ch) bb[ch] = b[ch * 16 + lr];

  // Stage + convert: 4096 float4 reads, swizzled bf16 writes.
  const float4* g4 = (const float4*)src;
  #pragma unroll
  for (int i = 0; i < 16; ++i) {
    int idx4 = i * 256 + t;
    float4 v = g4[idx4];
    int row = idx4 >> 6;             // 64 float4 per 256-elem row
    int k0 = (idx4 & 63) * 4;
    int gr = k0 >> 3;                // 16B granule index (8 bf16)
    int off = row * 512 + ((gr ^ (row & 15)) << 4) + (k0 & 7) * 2;
    uint32 lo = (uint32)f2bf(v.x) | ((uint32)f2bf(v.y) << 16);
    uint32 hi = (uint32)f2bf(v.z) | ((uint32)f2bf(v.w) << 16);
    uint2 pk; pk.x = lo; pk.y = hi;
    *(uint2*)(hb + off) = pk;
  }
  __syncthreads();

  short8 afr[8];
  #pragma unroll
  for (int kt = 0; kt < 8; ++kt) {
    int row = w * 16 + lr;
    int g = kt * 4 + lg;
    afr[kt] = *(const short8*)(hb + row * 512 + ((g ^ (row & 15)) << 4));
  }

  f32x4 acc[8];
  #pragma unroll
  for (int ch = 0; ch < 8; ++ch) acc[ch] = (f32x4){0.f, 0.f, 0.f, 0.f};
  #pragma unroll
  for (int ch = 0; ch < 8; ++ch) {
    #pragma unroll
    for (int kt = 0; kt < 8; ++kt) {
      short8 bf = *(const short8*)(Wtb + (size_t)(ch * 16 + lr) * HID + kt * 32 + lg * 8);
      acc[ch] = __builtin_amdgcn_mfma_f32_16x16x32_bf16(afr[kt], bf, acc[ch], 0, 0, 0);
    }
  }

  // Epilogue: rows w*16 + lg*4 + r, cols ch*16 + lr.
  #pragma unroll
  for (int r = 0; r < 4; ++r) {
    float v[8];
    float ss = 0.f;
    #pragma unroll
    for (int ch = 0; ch < 8; ++ch) {
      v[ch] = fmaxf(acc[ch][r] + bb[ch], 0.f);
      ss += v[ch] * v[ch];
    }
    ss += __shfl_xor(ss, 1, 64);
    ss += __shfl_xor(ss, 2, 64);
    ss += __shfl_xor(ss, 4, 64);
    ss += __shfl_xor(ss, 8, 64);
    float rn = rsqrtf(ss) * scale;
    int row = w * 16 + lg * 4 + r;
    #pragma unroll
    for (int ch = 0; ch < 8; ++ch)
      dst[(size_t)row * MI + ch * 16 + lr] = f2bf(v[ch] * rn);
  }
}

// ---------------------------------------------------------------------------
// Kernel 2: sim sweep, traffic-minimal by construction.
// Block = 512 threads (8 waves x 32 rows) owning 256 rows x 2048 cols.
// A frags (32 regs/lane) loaded from global ONCE; rowsums live in registers
// across the whole sweep (131K global atomics total). B tiles (128 cols,
// 32 KB) double-buffered in LDS via global_load_lds: prefetch jt+1 issued
// before compute of jt, so the barrier's vmcnt drain is covered by compute.
// Colsums: per-tile shfl-reduce -> ds_add into block-local 8 KB accumulator,
// flushed once at the end (1M global atomics total).
// Issued global traffic: A = 16 MB, B = 256 MB (vs 1.65 GB fetched in r4).
// ---------------------------------------------------------------------------
__global__ __launch_bounds__(512, 4) void sim_kernel(
    const ushort_t* __restrict__ p1b, const ushort_t* __restrict__ p2b,
    float* __restrict__ rowsum, float* __restrict__ colsum)
{
  __shared__ __align__(16) unsigned char ldsB[65536];   // 2 x 32 KB dbuf
  __shared__ float colacc[2048];                        // 8 KB
  int t = threadIdx.x;
  int lane = t & 63, w = t >> 6;          // 8 waves
  int lr = lane & 15, lg = lane >> 4;
  int rowbase = blockIdx.y * 256 + w * 32;   // wave owns 32 fixed rows
  int jbase = blockIdx.x * 2048;             // block owns 2048 cols

  // Stage tile jt into buffer buf (wave stages its contiguous 4 KB quarter).
  auto stage = [&](int buf, int jt) {
    int j0 = jbase + jt * 128;
    #pragma unroll
    for (int s = 0; s < 4; ++s) {
      int gidx = w * 256 + s * 64 + lane;   // 16B granule index in tile
      int row = gidx >> 4, gs = gidx & 15;
      const ushort_t* gp = p2b + (size_t)(j0 + row) * MI + ((gs ^ (row & 15)) << 3);
      unsigned char* lp = ldsB + buf * 32768 + w * 4096 + s * 1024;  // uniform
      __builtin_amdgcn_global_load_lds((const AS1 void*)gp, (AS3 void*)lp, 16, 0, 0);
    }
  };

  stage(0, 0);   // prefetch tile 0 first — latency overlapped with A-loads

  // A frags: 32 rows x K=128, held in registers for the whole kernel.
  short8 afr[2][4];
  #pragma unroll
  for (int rt = 0; rt < 2; ++rt)
    #pragma unroll
    for (int kt = 0; kt < 4; ++kt)
      afr[rt][kt] = *(const short8*)(p1b + (size_t)(rowbase + rt * 16 + lr) * MI + kt * 32 + lg * 8);

  #pragma unroll
  for (int i = 0; i < 4; ++i) colacc[i * 512 + t] = 0.f;

  f32x2 rs2[2][2];
  #pragma unroll
  for (int rt = 0; rt < 2; ++rt) {
    rs2[rt][0] = (f32x2){0.f, 0.f};
    rs2[rt][1] = (f32x2){0.f, 0.f};
  }

  __syncthreads();   // tile 0 staged, colacc zeroed

  for (int jt = 0; jt < 16; ++jt) {
    int cur = jt & 1;
    if (jt + 1 < 16) stage(1 - cur, jt + 1);   // prefetch next tile
    const unsigned char* B = ldsB + cur * 32768;

    #pragma unroll
    for (int ch = 0; ch < 8; ++ch) {
      f32x4 acc[2];
      acc[0] = (f32x4){0.f, 0.f, 0.f, 0.f};
      acc[1] = (f32x4){0.f, 0.f, 0.f, 0.f};
      #pragma unroll
      for (int kt = 0; kt < 4; ++kt) {
        int ncol = ch * 16 + lr;
        int g = kt * 4 + lg;
        short8 bf = *(const short8*)(B + ncol * 256 + ((g ^ (ncol & 15)) << 4));
        acc[0] = __builtin_amdgcn_mfma_f32_16x16x32_bf16(afr[0][kt], bf, acc[0], 0, 0, 0);
        acc[1] = __builtin_amdgcn_mfma_f32_16x16x32_bf16(afr[1][kt], bf, acc[1], 0, 0, 0);
      }
      // D layout: col = ch*16 + lr, row = rt*16 + lg*4 + reg.
      float csum = 0.f;
      #pragma unroll
      for (int rt = 0; rt < 2; ++rt) {
        f32x2 e01, e23;
        e01[0] = __builtin_amdgcn_exp2f(acc[rt][0]);
        e01[1] = __builtin_amdgcn_exp2f(acc[rt][1]);
        e23[0] = __builtin_amdgcn_exp2f(acc[rt][2]);
        e23[1] = __builtin_amdgcn_exp2f(acc[rt][3]);
        rs2[rt][0] += e01;
        rs2[rt][1] += e23;
        csum += (e01[0] + e01[1]) + (e23[0] + e23[1]);
      }
      // Column partial: reduce over the 4 lg groups, ds-atomic by lg==0.
      csum += __shfl_xor(csum, 16, 64);
      csum += __shfl_xor(csum, 32, 64);
      if (lg == 0) atomicAdd(&colacc[jt * 128 + ch * 16 + lr], csum);
    }
    __syncthreads();   // drains prefetch (covered by compute) + swap safety
  }

  // Row flush: butterfly over the 16 lr-lanes, one global atomic per row.
  #pragma unroll
  for (int rt = 0; rt < 2; ++rt)
    #pragma unroll
    for (int j = 0; j < 2; ++j)
      #pragma unroll
      for (int s = 0; s < 2; ++s) {
        float v = rs2[rt][j][s];
        v += __shfl_xor(v, 1, 64);
        v += __shfl_xor(v, 2, 64);
        v += __shfl_xor(v, 4, 64);
        v += __shfl_xor(v, 8, 64);
        if (lr == 0) atomicAdd(&rowsum[rowbase + rt * 16 + lg * 4 + j * 2 + s], v);
      }

  // Col flush: one global atomic per owned col.
  #pragma unroll
  for (int i = 0; i < 4; ++i) {
    int idx = i * 512 + t;
    atomicAdd(&colsum[jbase + idx], colacc[idx]);
  }
}

// ---------------------------------------------------------------------------
// Kernel 3: per-edge positive logits, both directions.
// d = ALPHA*cos (ALPHA folded into p1b). exp term = exp2(d); ln-logit = d*ln2.
// ---------------------------------------------------------------------------
__global__ __launch_bounds__(256) void edge_kernel(
    const int* __restrict__ pos_row, const int* __restrict__ pos_col,
    const ushort_t* __restrict__ p1b, const ushort_t* __restrict__ p2b,
    float* __restrict__ psum1, float* __restrict__ psum2,
    float* __restrict__ srow1, float* __restrict__ srow2,
    float* __restrict__ cntb, int E)
{
  int e = blockIdx.x * 256 + threadIdx.x;
  if (e >= E) return;
  int r = pos_row[e], c = pos_col[e];
  const uint4* a1 = (const uint4*)(p1b + (size_t)r * MI);
  const uint4* b1 = (const uint4*)(p2b + (size_t)c * MI);
  const uint4* a2 = (const uint4*)(p1b + (size_t)c * MI);
  const uint4* b2 = (const uint4*)(p2b + (size_t)r * MI);
  float d1 = 0.f, d2 = 0.f;
  #pragma unroll
  for (int it = 0; it < 16; ++it) {
    uint4 x = a1[it], y = b1[it];
    d1 += bflo(x.x) * bflo(y.x) + bfhi(x.x) * bfhi(y.x);
    d1 += bflo(x.y) * bflo(y.y) + bfhi(x.y) * bfhi(y.y);
    d1 += bflo(x.z) * bflo(y.z) + bfhi(x.z) * bfhi(y.z);
    d1 += bflo(x.w) * bflo(y.w) + bfhi(x.w) * bfhi(y.w);
    uint4 u = a2[it], v = b2[it];
    d2 += bflo(u.x) * bflo(v.x) + bfhi(u.x) * bfhi(v.x);
    d2 += bflo(u.y) * bflo(v.y) + bfhi(u.y) * bfhi(v.y);
    d2 += bflo(u.z) * bflo(v.z) + bfhi(u.z) * bfhi(v.z);
    d2 += bflo(u.w) * bflo(v.w) + bfhi(u.w) * bfhi(v.w);
  }
  float e1 = __builtin_amdgcn_exp2f(d1);
  float e2 = __builtin_amdgcn_exp2f(d2);
  atomicAdd(&psum1[r], e1);
  atomicAdd(&srow1[r], d1 * LN2F);
  atomicAdd(&psum2[r], e2);
  atomicAdd(&srow2[r], d2 * LN2F);
  atomicAdd(&cntb[r], 1.0f);
}

// ---------------------------------------------------------------------------
// Kernel 4: loss contribution per row, atomicAdd into out[0] (pre-zeroed).
// ---------------------------------------------------------------------------
__global__ __launch_bounds__(256) void finalize_kernel(
    const float* __restrict__ rowsum, const float* __restrict__ colsum,
    const float* __restrict__ psum1, const float* __restrict__ psum2,
    const float* __restrict__ srow1, const float* __restrict__ srow2,
    const float* __restrict__ cntb, float* __restrict__ out, int n)
{
  __shared__ float sred[4];
  int r = blockIdx.x * 256 + threadIdx.x;
  float local = 0.f;
  if (r < n) {
    float inv = 1.0f / cntb[r];
    float d1 = rowsum[r] - psum1[r];
    float d2 = colsum[r] - psum2[r];
    local = srow1[r] * inv - __builtin_amdgcn_logf(d1) * LN2F
          + srow2[r] * inv - __builtin_amdgcn_logf(d2) * LN2F;
  }
  #pragma unroll
  for (int m = 1; m <= 32; m <<= 1) local += __shfl_xor(local, m, 64);
  int lane = threadIdx.x & 63, wv = threadIdx.x >> 6;
  if (lane == 0) sred[wv] = local;
  __syncthreads();
  if (threadIdx.x == 0) {
    float tot = sred[0] + sred[1] + sred[2] + sred[3];
    atomicAdd(out, -tot / (2.0f * n));
  }
}

extern "C" void kernel_launch(void* const* d_in, const int* in_sizes, int n_in,
                              void* d_out, int out_size, void* d_ws, size_t ws_size,
                              hipStream_t stream)
{
  const float* h1 = (const float*)d_in[0];
  const float* h2 = (const float*)d_in[1];
  const float* W  = (const float*)d_in[2];
  const float* b  = (const float*)d_in[3];
  const int* pos_row = (const int*)d_in[4];
  const int* pos_col = (const int*)d_in[5];
  int n = in_sizes[0] / HID;      // 16384
  int E = in_sizes[4];            // 65536
  float* out = (float*)d_out;

  char* ws = (char*)d_ws;
  ushort_t* p1b = (ushort_t*)ws;                       // n*128 bf16 = 4 MB
  ushort_t* p2b = p1b + (size_t)n * MI;                // 4 MB
  float* fbase  = (float*)(ws + (size_t)2 * n * MI * sizeof(ushort_t));
  float* rowsum = fbase;
  float* colsum = rowsum + n;
  float* psum1  = colsum + n;
  float* psum2  = psum1 + n;
  float* srow1  = psum2 + n;
  float* srow2  = srow1 + n;
  float* cntb   = srow2 + n;
  ushort_t* Wtb = (ushort_t*)(cntb + n);               // 128x256 bf16 = 64 KB

  int nz = 7 * n;
  hipMemsetAsync(out, 0, sizeof(float), stream);
  prep_kernel<<<(nz + 255) / 256, 256, 0, stream>>>(W, Wtb, fbase, nz);
  proj_kernel<<<2 * n / 64, 256, 0, stream>>>(h1, h2, Wtb, b, p1b, p2b, n);
  dim3 g2(8, 64);                 // (colgroups, rowgroups)
  sim_kernel<<<g2, 512, 0, stream>>>(p1b, p2b, rowsum, colsum);
  edge_kernel<<<(E + 255) / 256, 256, 0, stream>>>(pos_row, pos_col, p1b, p2b,
                                                   psum1, psum2, srow1, srow2, cntb, E);
  finalize_kernel<<<(n + 255) / 256, 256, 0, stream>>>(rowsum, colsum, psum1, psum2,
                                                       srow1, srow2, cntb, out, n);
}

// Round 6
// 209.190 us; speedup vs baseline: 6.4246x; 1.0828x over previous
//
#include <hip/hip_runtime.h>

typedef unsigned short ushort_t;
typedef unsigned int uint32;
typedef __attribute__((ext_vector_type(8))) short short8;
typedef __attribute__((ext_vector_type(4))) float f32x4;
typedef __attribute__((ext_vector_type(2))) float f32x2;

#define HID 256
#define MI 128
// p1 is pre-scaled by ALPHA = 2/ln2, so sim MFMA output = cos*2/ln2 and
// exp(cos/T) = exp2(acc) directly. Edge ln-logit: s = 2*cos = d * ln2.
#define ALPHA 2.8853900817779268f
#define LN2F 0.69314718055994531f

#define AS1 __attribute__((address_space(1)))
#define AS3 __attribute__((address_space(3)))

__device__ __forceinline__ float bflo(uint32 u) { return __uint_as_float(u << 16); }
__device__ __forceinline__ float bfhi(uint32 u) { return __uint_as_float(u & 0xffff0000u); }
__device__ __forceinline__ ushort_t f2bf(float f) {
  uint32 u = __float_as_uint(f);
  u += 0x7fffu + ((u >> 16) & 1u);   // RNE
  return (ushort_t)(u >> 16);
}

// ---------------------------------------------------------------------------
// Kernel 0 (prep): Wt[n][k] (bf16) <- W[k][n] (f32), zero fbase[7n] + out.
// ---------------------------------------------------------------------------
__global__ __launch_bounds__(256) void prep_kernel(
    const float* __restrict__ W, ushort_t* __restrict__ Wtb,
    float* __restrict__ fbase, int nz, float* __restrict__ out)
{
  int idx = blockIdx.x * 256 + threadIdx.x;
  if (idx < HID * MI) {
    int k = idx >> 7, nn = idx & 127;
    Wtb[nn * HID + k] = f2bf(W[k * MI + nn]);   // read coalesced over nn
  }
  if (idx < nz) fbase[idx] = 0.f;
  if (idx == 0) out[0] = 0.f;
}

// ---------------------------------------------------------------------------
// Kernel 1: p = l2norm(relu(h @ W + b)) -> bf16 (p1 additionally * ALPHA).
// MFMA version: h cast to bf16 during LDS staging (XOR-swizzled), W-frags
// read from pre-transposed Wtb (64 KB, L2-hot). 64 rows/block, wave=16 rows.
// ---------------------------------------------------------------------------
__global__ __launch_bounds__(256) void proj_kernel(
    const float* __restrict__ h1, const float* __restrict__ h2,
    const ushort_t* __restrict__ Wtb, const float* __restrict__ b,
    ushort_t* __restrict__ p1b, ushort_t* __restrict__ p2b, int n)
{
  __shared__ __align__(16) unsigned char hb[64 * 512];   // 64 rows x 256 bf16
  int t = threadIdx.x;
  int lane = t & 63, w = t >> 6;
  int lr = lane & 15, lg = lane >> 4;
  long R0 = (long)blockIdx.x * 64;
  const float* src = (R0 < n) ? (h1 + R0 * HID) : (h2 + (R0 - n) * HID);
  ushort_t* dst = (R0 < n) ? (p1b + R0 * MI) : (p2b + (R0 - n) * MI);
  float scale = (R0 < n) ? ALPHA : 1.0f;

  float bb[8];
  #pragma unroll
  for (int ch = 0; ch < 8; ++ch) bb[ch] = b[ch * 16 + lr];

  // Stage + convert: 4096 float4 reads, swizzled bf16 writes.
  const float4* g4 = (const float4*)src;
  #pragma unroll
  for (int i = 0; i < 16; ++i) {
    int idx4 = i * 256 + t;
    float4 v = g4[idx4];
    int row = idx4 >> 6;             // 64 float4 per 256-elem row
    int k0 = (idx4 & 63) * 4;
    int gr = k0 >> 3;                // 16B granule index (8 bf16)
    int off = row * 512 + ((gr ^ (row & 15)) << 4) + (k0 & 7) * 2;
    uint32 lo = (uint32)f2bf(v.x) | ((uint32)f2bf(v.y) << 16);
    uint32 hi = (uint32)f2bf(v.z) | ((uint32)f2bf(v.w) << 16);
    uint2 pk; pk.x = lo; pk.y = hi;
    *(uint2*)(hb + off) = pk;
  }
  __syncthreads();

  short8 afr[8];
  #pragma unroll
  for (int kt = 0; kt < 8; ++kt) {
    int row = w * 16 + lr;
    int g = kt * 4 + lg;
    afr[kt] = *(const short8*)(hb + row * 512 + ((g ^ (row & 15)) << 4));
  }

  f32x4 acc[8];
  #pragma unroll
  for (int ch = 0; ch < 8; ++ch) acc[ch] = (f32x4){0.f, 0.f, 0.f, 0.f};
  #pragma unroll
  for (int ch = 0; ch < 8; ++ch) {
    #pragma unroll
    for (int kt = 0; kt < 8; ++kt) {
      short8 bf = *(const short8*)(Wtb + (size_t)(ch * 16 + lr) * HID + kt * 32 + lg * 8);
      acc[ch] = __builtin_amdgcn_mfma_f32_16x16x32_bf16(afr[kt], bf, acc[ch], 0, 0, 0);
    }
  }

  // Epilogue: rows w*16 + lg*4 + r, cols ch*16 + lr.
  #pragma unroll
  for (int r = 0; r < 4; ++r) {
    float v[8];
    float ss = 0.f;
    #pragma unroll
    for (int ch = 0; ch < 8; ++ch) {
      v[ch] = fmaxf(acc[ch][r] + bb[ch], 0.f);
      ss += v[ch] * v[ch];
    }
    ss += __shfl_xor(ss, 1, 64);
    ss += __shfl_xor(ss, 2, 64);
    ss += __shfl_xor(ss, 4, 64);
    ss += __shfl_xor(ss, 8, 64);
    float rn = rsqrtf(ss) * scale;
    int row = w * 16 + lg * 4 + r;
    #pragma unroll
    for (int ch = 0; ch < 8; ++ch)
      dst[(size_t)row * MI + ch * 16 + lr] = f2bf(v[ch] * rn);
  }
}

// ---------------------------------------------------------------------------
// Kernel 2: sim sweep. Same traffic-minimal structure as r5 but tuned for
// occupancy: B tile = 64 cols (16 KB), chunk = 1024 cols, LDS = 2x16 KB dbuf
// + 4 KB colacc = 36 KB -> 4 blocks/CU = 32 waves/CU (vs 16 in r5).
// Block = 512 threads (8 waves x 32 rows) owning 256 rows x 1024 cols.
// A frags in registers once; rowsums in registers across the whole sweep.
// ---------------------------------------------------------------------------
__global__ __launch_bounds__(512, 4) void sim_kernel(
    const ushort_t* __restrict__ p1b, const ushort_t* __restrict__ p2b,
    float* __restrict__ rowsum, float* __restrict__ colsum)
{
  __shared__ __align__(16) unsigned char ldsB[32768];   // 2 x 16 KB dbuf
  __shared__ float colacc[1024];                        // 4 KB
  int t = threadIdx.x;
  int lane = t & 63, w = t >> 6;          // 8 waves
  int lr = lane & 15, lg = lane >> 4;
  int rowbase = blockIdx.y * 256 + w * 32;   // wave owns 32 fixed rows
  int jbase = blockIdx.x * 1024;             // block owns 1024 cols

  // Stage tile jt (64 cols x 128 K = 16 KB = 1024 granules) into buffer buf.
  auto stage = [&](int buf, int jt) {
    int j0 = jbase + jt * 64;
    #pragma unroll
    for (int s = 0; s < 2; ++s) {
      int gidx = s * 512 + w * 64 + lane;   // 16B granule index in tile
      int row = gidx >> 4, gs = gidx & 15;
      const ushort_t* gp = p2b + (size_t)(j0 + row) * MI + ((gs ^ (row & 15)) << 3);
      unsigned char* lp = ldsB + buf * 16384 + s * 8192 + w * 1024;  // uniform
      __builtin_amdgcn_global_load_lds((const AS1 void*)gp, (AS3 void*)lp, 16, 0, 0);
    }
  };

  stage(0, 0);   // prefetch tile 0 — latency overlapped with A-loads

  // A frags: 32 rows x K=128, held in registers for the whole kernel.
  short8 afr[2][4];
  #pragma unroll
  for (int rt = 0; rt < 2; ++rt)
    #pragma unroll
    for (int kt = 0; kt < 4; ++kt)
      afr[rt][kt] = *(const short8*)(p1b + (size_t)(rowbase + rt * 16 + lr) * MI + kt * 32 + lg * 8);

  colacc[t] = 0.f;
  colacc[512 + t] = 0.f;

  f32x2 rs2[2][2];
  #pragma unroll
  for (int rt = 0; rt < 2; ++rt) {
    rs2[rt][0] = (f32x2){0.f, 0.f};
    rs2[rt][1] = (f32x2){0.f, 0.f};
  }

  __syncthreads();   // tile 0 staged, colacc zeroed

  for (int jt = 0; jt < 16; ++jt) {
    int cur = jt & 1;
    if (jt + 1 < 16) stage(1 - cur, jt + 1);   // prefetch next tile
    const unsigned char* B = ldsB + cur * 16384;

    #pragma unroll
    for (int ch = 0; ch < 4; ++ch) {
      f32x4 acc[2];
      acc[0] = (f32x4){0.f, 0.f, 0.f, 0.f};
      acc[1] = (f32x4){0.f, 0.f, 0.f, 0.f};
      #pragma unroll
      for (int kt = 0; kt < 4; ++kt) {
        int ncol = ch * 16 + lr;
        int g = kt * 4 + lg;
        short8 bf = *(const short8*)(B + ncol * 256 + ((g ^ (ncol & 15)) << 4));
        acc[0] = __builtin_amdgcn_mfma_f32_16x16x32_bf16(afr[0][kt], bf, acc[0], 0, 0, 0);
        acc[1] = __builtin_amdgcn_mfma_f32_16x16x32_bf16(afr[1][kt], bf, acc[1], 0, 0, 0);
      }
      // D layout: col = ch*16 + lr, row = rt*16 + lg*4 + reg.
      f32x2 cs2 = (f32x2){0.f, 0.f};
      #pragma unroll
      for (int rt = 0; rt < 2; ++rt) {
        f32x2 e01, e23;
        e01[0] = __builtin_amdgcn_exp2f(acc[rt][0]);
        e01[1] = __builtin_amdgcn_exp2f(acc[rt][1]);
        e23[0] = __builtin_amdgcn_exp2f(acc[rt][2]);
        e23[1] = __builtin_amdgcn_exp2f(acc[rt][3]);
        rs2[rt][0] += e01;
        rs2[rt][1] += e23;
        cs2 += e01;
        cs2 += e23;
      }
      // Column partial: reduce over the 4 lg groups, ds-atomic by lg==0.
      float csum = cs2[0] + cs2[1];
      csum += __shfl_xor(csum, 16, 64);
      csum += __shfl_xor(csum, 32, 64);
      if (lg == 0) atomicAdd(&colacc[jt * 64 + ch * 16 + lr], csum);
    }
    __syncthreads();   // swap safety; prefetch drain covered by compute
  }

  // Row flush: butterfly over the 16 lr-lanes, one global atomic per row.
  #pragma unroll
  for (int rt = 0; rt < 2; ++rt)
    #pragma unroll
    for (int j = 0; j < 2; ++j)
      #pragma unroll
      for (int s = 0; s < 2; ++s) {
        float v = rs2[rt][j][s];
        v += __shfl_xor(v, 1, 64);
        v += __shfl_xor(v, 2, 64);
        v += __shfl_xor(v, 4, 64);
        v += __shfl_xor(v, 8, 64);
        if (lr == 0) atomicAdd(&rowsum[rowbase + rt * 16 + lg * 4 + j * 2 + s], v);
      }

  // Col flush: one global atomic per owned col.
  atomicAdd(&colsum[jbase + t], colacc[t]);
  atomicAdd(&colsum[jbase + 512 + t], colacc[512 + t]);
}

// ---------------------------------------------------------------------------
// Kernel 3: per-edge positive logits, both directions. 4 lanes per edge:
// lane q reads 64B (4 x uint4) of each operand -> coalesced 64B group reads;
// shfl-reduce over the 4-lane group; lane q==0 does the atomics.
// ---------------------------------------------------------------------------
__global__ __launch_bounds__(256) void edge_kernel(
    const int* __restrict__ pos_row, const int* __restrict__ pos_col,
    const ushort_t* __restrict__ p1b, const ushort_t* __restrict__ p2b,
    float* __restrict__ psum1, float* __restrict__ psum2,
    float* __restrict__ srow1, float* __restrict__ srow2,
    float* __restrict__ cntb, int E)
{
  int tid = blockIdx.x * 256 + threadIdx.x;
  int e = tid >> 2, q = tid & 3;
  if (e >= E) return;
  int r = pos_row[e], c = pos_col[e];
  const uint4* a1 = (const uint4*)(p1b + (size_t)r * MI) + q * 4;
  const uint4* b1 = (const uint4*)(p2b + (size_t)c * MI) + q * 4;
  const uint4* a2 = (const uint4*)(p1b + (size_t)c * MI) + q * 4;
  const uint4* b2 = (const uint4*)(p2b + (size_t)r * MI) + q * 4;
  float d1 = 0.f, d2 = 0.f;
  #pragma unroll
  for (int it = 0; it < 4; ++it) {
    uint4 x = a1[it], y = b1[it];
    d1 += bflo(x.x) * bflo(y.x) + bfhi(x.x) * bfhi(y.x);
    d1 += bflo(x.y) * bflo(y.y) + bfhi(x.y) * bfhi(y.y);
    d1 += bflo(x.z) * bflo(y.z) + bfhi(x.z) * bfhi(y.z);
    d1 += bflo(x.w) * bflo(y.w) + bfhi(x.w) * bfhi(y.w);
    uint4 u = a2[it], v = b2[it];
    d2 += bflo(u.x) * bflo(v.x) + bfhi(u.x) * bfhi(v.x);
    d2 += bflo(u.y) * bflo(v.y) + bfhi(u.y) * bfhi(v.y);
    d2 += bflo(u.z) * bflo(v.z) + bfhi(u.z) * bfhi(v.z);
    d2 += bflo(u.w) * bflo(v.w) + bfhi(u.w) * bfhi(v.w);
  }
  d1 += __shfl_xor(d1, 1, 64);
  d1 += __shfl_xor(d1, 2, 64);
  d2 += __shfl_xor(d2, 1, 64);
  d2 += __shfl_xor(d2, 2, 64);
  if (q == 0) {
    float e1 = __builtin_amdgcn_exp2f(d1);
    float e2 = __builtin_amdgcn_exp2f(d2);
    atomicAdd(&psum1[r], e1);
    atomicAdd(&srow1[r], d1 * LN2F);
    atomicAdd(&psum2[r], e2);
    atomicAdd(&srow2[r], d2 * LN2F);
    atomicAdd(&cntb[r], 1.0f);
  }
}

// ---------------------------------------------------------------------------
// Kernel 4: loss contribution per row, atomicAdd into out[0] (pre-zeroed).
// ---------------------------------------------------------------------------
__global__ __launch_bounds__(256) void finalize_kernel(
    const float* __restrict__ rowsum, const float* __restrict__ colsum,
    const float* __restrict__ psum1, const float* __restrict__ psum2,
    const float* __restrict__ srow1, const float* __restrict__ srow2,
    const float* __restrict__ cntb, float* __restrict__ out, int n)
{
  __shared__ float sred[4];
  int r = blockIdx.x * 256 + threadIdx.x;
  float local = 0.f;
  if (r < n) {
    float inv = 1.0f / cntb[r];
    float d1 = rowsum[r] - psum1[r];
    float d2 = colsum[r] - psum2[r];
    local = srow1[r] * inv - __builtin_amdgcn_logf(d1) * LN2F
          + srow2[r] * inv - __builtin_amdgcn_logf(d2) * LN2F;
  }
  #pragma unroll
  for (int m = 1; m <= 32; m <<= 1) local += __shfl_xor(local, m, 64);
  int lane = threadIdx.x & 63, wv = threadIdx.x >> 6;
  if (lane == 0) sred[wv] = local;
  __syncthreads();
  if (threadIdx.x == 0) {
    float tot = sred[0] + sred[1] + sred[2] + sred[3];
    atomicAdd(out, -tot / (2.0f * n));
  }
}

extern "C" void kernel_launch(void* const* d_in, const int* in_sizes, int n_in,
                              void* d_out, int out_size, void* d_ws, size_t ws_size,
                              hipStream_t stream)
{
  const float* h1 = (const float*)d_in[0];
  const float* h2 = (const float*)d_in[1];
  const float* W  = (const float*)d_in[2];
  const float* b  = (const float*)d_in[3];
  const int* pos_row = (const int*)d_in[4];
  const int* pos_col = (const int*)d_in[5];
  int n = in_sizes[0] / HID;      // 16384
  int E = in_sizes[4];            // 65536
  float* out = (float*)d_out;

  char* ws = (char*)d_ws;
  ushort_t* p1b = (ushort_t*)ws;                       // n*128 bf16 = 4 MB
  ushort_t* p2b = p1b + (size_t)n * MI;                // 4 MB
  float* fbase  = (float*)(ws + (size_t)2 * n * MI * sizeof(ushort_t));
  float* rowsum = fbase;
  float* colsum = rowsum + n;
  float* psum1  = colsum + n;
  float* psum2  = psum1 + n;
  float* srow1  = psum2 + n;
  float* srow2  = srow1 + n;
  float* cntb   = srow2 + n;
  ushort_t* Wtb = (ushort_t*)(cntb + n);               // 128x256 bf16 = 64 KB

  int nz = 7 * n;
  prep_kernel<<<(nz + 255) / 256, 256, 0, stream>>>(W, Wtb, fbase, nz, out);
  proj_kernel<<<2 * n / 64, 256, 0, stream>>>(h1, h2, Wtb, b, p1b, p2b, n);
  dim3 g2(n / 1024, n / 256);     // (colgroups, rowgroups) = (16, 64)
  sim_kernel<<<g2, 512, 0, stream>>>(p1b, p2b, rowsum, colsum);
  edge_kernel<<<(E * 4 + 255) / 256, 256, 0, stream>>>(pos_row, pos_col, p1b, p2b,
                                                       psum1, psum2, srow1, srow2, cntb, E);
  finalize_kernel<<<(n + 255) / 256, 256, 0, stream>>>(rowsum, colsum, psum1, psum2,
                                                       srow1, srow2, cntb, out, n);
}

// Round 7
// 206.736 us; speedup vs baseline: 6.5009x; 1.0119x over previous
//
#include <hip/hip_runtime.h>

typedef unsigned short ushort_t;
typedef unsigned int uint32;
typedef __attribute__((ext_vector_type(8))) short short8;
typedef __attribute__((ext_vector_type(4))) float f32x4;
typedef __attribute__((ext_vector_type(2))) float f32x2;

#define HID 256
#define MI 128
// p1 is pre-scaled by ALPHA = 2/ln2, so sim MFMA output = cos*2/ln2 and
// exp(cos/T) = exp2(acc) directly. Edge ln-logit: s = 2*cos = d * ln2.
#define ALPHA 2.8853900817779268f
#define LN2F 0.69314718055994531f

__device__ __forceinline__ float bflo(uint32 u) { return __uint_as_float(u << 16); }
__device__ __forceinline__ float bfhi(uint32 u) { return __uint_as_float(u & 0xffff0000u); }
__device__ __forceinline__ ushort_t f2bf(float f) {
  uint32 u = __float_as_uint(f);
  u += 0x7fffu + ((u >> 16) & 1u);   // RNE
  return (ushort_t)(u >> 16);
}

// ---------------------------------------------------------------------------
// Kernel 0 (prep): Wt[n][k] (bf16) <- W[k][n] (f32), zero fbase[7n] + out.
// ---------------------------------------------------------------------------
__global__ __launch_bounds__(256) void prep_kernel(
    const float* __restrict__ W, ushort_t* __restrict__ Wtb,
    float* __restrict__ fbase, int nz, float* __restrict__ out)
{
  int idx = blockIdx.x * 256 + threadIdx.x;
  if (idx < HID * MI) {
    int k = idx >> 7, nn = idx & 127;
    Wtb[nn * HID + k] = f2bf(W[k * MI + nn]);   // read coalesced over nn
  }
  if (idx < nz) fbase[idx] = 0.f;
  if (idx == 0) out[0] = 0.f;
}

// ---------------------------------------------------------------------------
// Kernel 1: p = l2norm(relu(h @ W + b)) -> bf16 (p1 additionally * ALPHA).
// MFMA version: h cast to bf16 during LDS staging (XOR-swizzled), W-frags
// read from pre-transposed Wtb (64 KB, L2-hot). 64 rows/block, wave=16 rows.
// ---------------------------------------------------------------------------
__global__ __launch_bounds__(256) void proj_kernel(
    const float* __restrict__ h1, const float* __restrict__ h2,
    const ushort_t* __restrict__ Wtb, const float* __restrict__ b,
    ushort_t* __restrict__ p1b, ushort_t* __restrict__ p2b, int n)
{
  __shared__ __align__(16) unsigned char hb[64 * 512];   // 64 rows x 256 bf16
  int t = threadIdx.x;
  int lane = t & 63, w = t >> 6;
  int lr = lane & 15, lg = lane >> 4;
  long R0 = (long)blockIdx.x * 64;
  const float* src = (R0 < n) ? (h1 + R0 * HID) : (h2 + (R0 - n) * HID);
  ushort_t* dst = (R0 < n) ? (p1b + R0 * MI) : (p2b + (R0 - n) * MI);
  float scale = (R0 < n) ? ALPHA : 1.0f;

  float bb[8];
  #pragma unroll
  for (int ch = 0; ch < 8; ++ch) bb[ch] = b[ch * 16 + lr];

  // Stage + convert: 4096 float4 reads, swizzled bf16 writes.
  const float4* g4 = (const float4*)src;
  #pragma unroll
  for (int i = 0; i < 16; ++i) {
    int idx4 = i * 256 + t;
    float4 v = g4[idx4];
    int row = idx4 >> 6;             // 64 float4 per 256-elem row
    int k0 = (idx4 & 63) * 4;
    int gr = k0 >> 3;                // 16B granule index (8 bf16)
    int off = row * 512 + ((gr ^ (row & 15)) << 4) + (k0 & 7) * 2;
    uint32 lo = (uint32)f2bf(v.x) | ((uint32)f2bf(v.y) << 16);
    uint32 hi = (uint32)f2bf(v.z) | ((uint32)f2bf(v.w) << 16);
    uint2 pk; pk.x = lo; pk.y = hi;
    *(uint2*)(hb + off) = pk;
  }
  __syncthreads();

  short8 afr[8];
  #pragma unroll
  for (int kt = 0; kt < 8; ++kt) {
    int row = w * 16 + lr;
    int g = kt * 4 + lg;
    afr[kt] = *(const short8*)(hb + row * 512 + ((g ^ (row & 15)) << 4));
  }

  f32x4 acc[8];
  #pragma unroll
  for (int ch = 0; ch < 8; ++ch) acc[ch] = (f32x4){0.f, 0.f, 0.f, 0.f};
  #pragma unroll
  for (int ch = 0; ch < 8; ++ch) {
    #pragma unroll
    for (int kt = 0; kt < 8; ++kt) {
      short8 bf = *(const short8*)(Wtb + (size_t)(ch * 16 + lr) * HID + kt * 32 + lg * 8);
      acc[ch] = __builtin_amdgcn_mfma_f32_16x16x32_bf16(afr[kt], bf, acc[ch], 0, 0, 0);
    }
  }

  // Epilogue: rows w*16 + lg*4 + r, cols ch*16 + lr.
  #pragma unroll
  for (int r = 0; r < 4; ++r) {
    float v[8];
    float ss = 0.f;
    #pragma unroll
    for (int ch = 0; ch < 8; ++ch) {
      v[ch] = fmaxf(acc[ch][r] + bb[ch], 0.f);
      ss += v[ch] * v[ch];
    }
    ss += __shfl_xor(ss, 1, 64);
    ss += __shfl_xor(ss, 2, 64);
    ss += __shfl_xor(ss, 4, 64);
    ss += __shfl_xor(ss, 8, 64);
    float rn = rsqrtf(ss) * scale;
    int row = w * 16 + lg * 4 + r;
    #pragma unroll
    for (int ch = 0; ch < 8; ++ch)
      dst[(size_t)row * MI + ch * 16 + lr] = f2bf(v[ch] * rn);
  }
}

// ---------------------------------------------------------------------------
// Kernel 2: sim sweep, r6 structure but staging via global->VGPR->ds_write
// double-buffer (NOT global_load_lds): the barrier then only waits on fast
// LDS writes, never on a vmcnt(0) drain of in-flight global loads — the
// load latency for tile jt+1 is covered by the compute of tile jt.
// Block = 512 threads (8 waves x 32 rows) owning 256 rows x 1024 cols.
// A frags in registers once; rowsums in registers across the whole sweep.
// LDS: 2 x 16 KB B-dbuf + 4 KB colacc = 36 KB.
// ---------------------------------------------------------------------------
__global__ __launch_bounds__(512, 4) void sim_kernel(
    const ushort_t* __restrict__ p1b, const ushort_t* __restrict__ p2b,
    float* __restrict__ rowsum, float* __restrict__ colsum)
{
  __shared__ __align__(16) unsigned char ldsB[32768];   // 2 x 16 KB dbuf
  __shared__ float colacc[1024];                        // 4 KB
  int t = threadIdx.x;
  int lane = t & 63, w = t >> 6;          // 8 waves
  int lr = lane & 15, lg = lane >> 4;
  int rowbase = blockIdx.y * 256 + w * 32;   // wave owns 32 fixed rows
  int jbase = blockIdx.x * 1024;             // block owns 1024 cols

  // Staging registers: 2 granules of 16B per thread per tile.
  uint4 st0, st1;
  int g0 = t, g1 = t + 512;                  // granule ids in [0,1024)
  int row0 = g0 >> 4, gs0 = g0 & 15;
  int row1 = g1 >> 4, gs1 = g1 & 15;

  // Coalesced global read of tile jt (no permutation on the global side).
  auto load_stage = [&](int jt) {
    int j0 = jbase + jt * 64;
    st0 = *(const uint4*)(p2b + (size_t)(j0 + row0) * MI + (gs0 << 3));
    st1 = *(const uint4*)(p2b + (size_t)(j0 + row1) * MI + (gs1 << 3));
  };
  // XOR-swizzled LDS write: slot s holds global granule s^(row&15).
  auto write_stage = [&](int buf) {
    *(uint4*)(ldsB + buf * 16384 + row0 * 256 + ((gs0 ^ (row0 & 15)) << 4)) = st0;
    *(uint4*)(ldsB + buf * 16384 + row1 * 256 + ((gs1 ^ (row1 & 15)) << 4)) = st1;
  };

  load_stage(0);

  // A frags: 32 rows x K=128, held in registers for the whole kernel.
  short8 afr[2][4];
  #pragma unroll
  for (int rt = 0; rt < 2; ++rt)
    #pragma unroll
    for (int kt = 0; kt < 4; ++kt)
      afr[rt][kt] = *(const short8*)(p1b + (size_t)(rowbase + rt * 16 + lr) * MI + kt * 32 + lg * 8);

  colacc[t] = 0.f;
  colacc[512 + t] = 0.f;

  f32x2 rs2[2][2];
  #pragma unroll
  for (int rt = 0; rt < 2; ++rt) {
    rs2[rt][0] = (f32x2){0.f, 0.f};
    rs2[rt][1] = (f32x2){0.f, 0.f};
  }

  write_stage(0);
  __syncthreads();   // tile 0 staged, colacc zeroed

  for (int jt = 0; jt < 16; ++jt) {
    int cur = jt & 1;
    if (jt + 1 < 16) load_stage(jt + 1);   // global->VGPR, covered by compute
    const unsigned char* B = ldsB + cur * 16384;

    #pragma unroll
    for (int ch = 0; ch < 4; ++ch) {
      f32x4 acc[2];
      acc[0] = (f32x4){0.f, 0.f, 0.f, 0.f};
      acc[1] = (f32x4){0.f, 0.f, 0.f, 0.f};
      #pragma unroll
      for (int kt = 0; kt < 4; ++kt) {
        int ncol = ch * 16 + lr;
        int g = kt * 4 + lg;
        short8 bf = *(const short8*)(B + ncol * 256 + ((g ^ (ncol & 15)) << 4));
        acc[0] = __builtin_amdgcn_mfma_f32_16x16x32_bf16(afr[0][kt], bf, acc[0], 0, 0, 0);
        acc[1] = __builtin_amdgcn_mfma_f32_16x16x32_bf16(afr[1][kt], bf, acc[1], 0, 0, 0);
      }
      // D layout: col = ch*16 + lr, row = rt*16 + lg*4 + reg.
      f32x2 cs2 = (f32x2){0.f, 0.f};
      #pragma unroll
      for (int rt = 0; rt < 2; ++rt) {
        f32x2 e01, e23;
        e01[0] = __builtin_amdgcn_exp2f(acc[rt][0]);
        e01[1] = __builtin_amdgcn_exp2f(acc[rt][1]);
        e23[0] = __builtin_amdgcn_exp2f(acc[rt][2]);
        e23[1] = __builtin_amdgcn_exp2f(acc[rt][3]);
        rs2[rt][0] += e01;
        rs2[rt][1] += e23;
        cs2 += e01;
        cs2 += e23;
      }
      // Column partial: reduce over the 4 lg groups, ds-atomic by lg==0.
      float csum = cs2[0] + cs2[1];
      csum += __shfl_xor(csum, 16, 64);
      csum += __shfl_xor(csum, 32, 64);
      if (lg == 0) atomicAdd(&colacc[jt * 64 + ch * 16 + lr], csum);
    }
    if (jt + 1 < 16) write_stage(1 - cur);  // waits vmcnt here (covered)
    __syncthreads();   // lgkmcnt-only barrier: ds_writes + reads ordered
  }

  // Row flush: butterfly over the 16 lr-lanes, one global atomic per row.
  #pragma unroll
  for (int rt = 0; rt < 2; ++rt)
    #pragma unroll
    for (int j = 0; j < 2; ++j)
      #pragma unroll
      for (int s = 0; s < 2; ++s) {
        float v = rs2[rt][j][s];
        v += __shfl_xor(v, 1, 64);
        v += __shfl_xor(v, 2, 64);
        v += __shfl_xor(v, 4, 64);
        v += __shfl_xor(v, 8, 64);
        if (lr == 0) atomicAdd(&rowsum[rowbase + rt * 16 + lg * 4 + j * 2 + s], v);
      }

  // Col flush: one global atomic per owned col.
  atomicAdd(&colsum[jbase + t], colacc[t]);
  atomicAdd(&colsum[jbase + 512 + t], colacc[512 + t]);
}

// ---------------------------------------------------------------------------
// Kernel 3: per-edge positive logits, both directions. 4 lanes per edge:
// lane q reads 64B (4 x uint4) of each operand -> coalesced 64B group reads;
// shfl-reduce over the 4-lane group; lane q==0 does the atomics.
// ---------------------------------------------------------------------------
__global__ __launch_bounds__(256) void edge_kernel(
    const int* __restrict__ pos_row, const int* __restrict__ pos_col,
    const ushort_t* __restrict__ p1b, const ushort_t* __restrict__ p2b,
    float* __restrict__ psum1, float* __restrict__ psum2,
    float* __restrict__ srow1, float* __restrict__ srow2,
    float* __restrict__ cntb, int E)
{
  int tid = blockIdx.x * 256 + threadIdx.x;
  int e = tid >> 2, q = tid & 3;
  if (e >= E) return;
  int r = pos_row[e], c = pos_col[e];
  const uint4* a1 = (const uint4*)(p1b + (size_t)r * MI) + q * 4;
  const uint4* b1 = (const uint4*)(p2b + (size_t)c * MI) + q * 4;
  const uint4* a2 = (const uint4*)(p1b + (size_t)c * MI) + q * 4;
  const uint4* b2 = (const uint4*)(p2b + (size_t)r * MI) + q * 4;
  float d1 = 0.f, d2 = 0.f;
  #pragma unroll
  for (int it = 0; it < 4; ++it) {
    uint4 x = a1[it], y = b1[it];
    d1 += bflo(x.x) * bflo(y.x) + bfhi(x.x) * bfhi(y.x);
    d1 += bflo(x.y) * bflo(y.y) + bfhi(x.y) * bfhi(y.y);
    d1 += bflo(x.z) * bflo(y.z) + bfhi(x.z) * bfhi(y.z);
    d1 += bflo(x.w) * bflo(y.w) + bfhi(x.w) * bfhi(y.w);
    uint4 u = a2[it], v = b2[it];
    d2 += bflo(u.x) * bflo(v.x) + bfhi(u.x) * bfhi(v.x);
    d2 += bflo(u.y) * bflo(v.y) + bfhi(u.y) * bfhi(v.y);
    d2 += bflo(u.z) * bflo(v.z) + bfhi(u.z) * bfhi(v.z);
    d2 += bflo(u.w) * bflo(v.w) + bfhi(u.w) * bfhi(v.w);
  }
  d1 += __shfl_xor(d1, 1, 64);
  d1 += __shfl_xor(d1, 2, 64);
  d2 += __shfl_xor(d2, 1, 64);
  d2 += __shfl_xor(d2, 2, 64);
  if (q == 0) {
    float e1 = __builtin_amdgcn_exp2f(d1);
    float e2 = __builtin_amdgcn_exp2f(d2);
    atomicAdd(&psum1[r], e1);
    atomicAdd(&srow1[r], d1 * LN2F);
    atomicAdd(&psum2[r], e2);
    atomicAdd(&srow2[r], d2 * LN2F);
    atomicAdd(&cntb[r], 1.0f);
  }
}

// ---------------------------------------------------------------------------
// Kernel 4: loss contribution per row, atomicAdd into out[0] (pre-zeroed).
// ---------------------------------------------------------------------------
__global__ __launch_bounds__(256) void finalize_kernel(
    const float* __restrict__ rowsum, const float* __restrict__ colsum,
    const float* __restrict__ psum1, const float* __restrict__ psum2,
    const float* __restrict__ srow1, const float* __restrict__ srow2,
    const float* __restrict__ cntb, float* __restrict__ out, int n)
{
  __shared__ float sred[4];
  int r = blockIdx.x * 256 + threadIdx.x;
  float local = 0.f;
  if (r < n) {
    float inv = 1.0f / cntb[r];
    float d1 = rowsum[r] - psum1[r];
    float d2 = colsum[r] - psum2[r];
    local = srow1[r] * inv - __builtin_amdgcn_logf(d1) * LN2F
          + srow2[r] * inv - __builtin_amdgcn_logf(d2) * LN2F;
  }
  #pragma unroll
  for (int m = 1; m <= 32; m <<= 1) local += __shfl_xor(local, m, 64);
  int lane = threadIdx.x & 63, wv = threadIdx.x >> 6;
  if (lane == 0) sred[wv] = local;
  __syncthreads();
  if (threadIdx.x == 0) {
    float tot = sred[0] + sred[1] + sred[2] + sred[3];
    atomicAdd(out, -tot / (2.0f * n));
  }
}

extern "C" void kernel_launch(void* const* d_in, const int* in_sizes, int n_in,
                              void* d_out, int out_size, void* d_ws, size_t ws_size,
                              hipStream_t stream)
{
  const float* h1 = (const float*)d_in[0];
  const float* h2 = (const float*)d_in[1];
  const float* W  = (const float*)d_in[2];
  const float* b  = (const float*)d_in[3];
  const int* pos_row = (const int*)d_in[4];
  const int* pos_col = (const int*)d_in[5];
  int n = in_sizes[0] / HID;      // 16384
  int E = in_sizes[4];            // 65536
  float* out = (float*)d_out;

  char* ws = (char*)d_ws;
  ushort_t* p1b = (ushort_t*)ws;                       // n*128 bf16 = 4 MB
  ushort_t* p2b = p1b + (size_t)n * MI;                // 4 MB
  float* fbase  = (float*)(ws + (size_t)2 * n * MI * sizeof(ushort_t));
  float* rowsum = fbase;
  float* colsum = rowsum + n;
  float* psum1  = colsum + n;
  float* psum2  = psum1 + n;
  float* srow1  = psum2 + n;
  float* srow2  = srow1 + n;
  float* cntb   = srow2 + n;
  ushort_t* Wtb = (ushort_t*)(cntb + n);               // 128x256 bf16 = 64 KB

  int nz = 7 * n;
  prep_kernel<<<(nz + 255) / 256, 256, 0, stream>>>(W, Wtb, fbase, nz, out);
  proj_kernel<<<2 * n / 64, 256, 0, stream>>>(h1, h2, Wtb, b, p1b, p2b, n);
  dim3 g2(n / 1024, n / 256);     // (colgroups, rowgroups) = (16, 64)
  sim_kernel<<<g2, 512, 0, stream>>>(p1b, p2b, rowsum, colsum);
  edge_kernel<<<(E * 4 + 255) / 256, 256, 0, stream>>>(pos_row, pos_col, p1b, p2b,
                                                       psum1, psum2, srow1, srow2, cntb, E);
  finalize_kernel<<<(n + 255) / 256, 256, 0, stream>>>(rowsum, colsum, psum1, psum2,
                                                       srow1, srow2, cntb, out, n);
}